// Round 7
// baseline (184.232 us; speedup 1.0000x reference)
//
#include <hip/hip_runtime.h>
#include <stdint.h>

namespace {
constexpr int BATCH  = 512;
constexpr int CBS    = 320;       // combined batch size
constexpr int R      = 64;        // rank == wave size, lane = r
constexpr int K      = 4096;
constexpr int NADAPT = 80;
constexpr int SPLIT  = 32;        // k-split across waves
constexpr int KS     = K / SPLIT; // 128 k per wave
constexpr int NBODY  = KS / 32;   // 4 bodies of 32 k
constexpr int G      = 4;         // combos grouped per wave (share one adapter)
constexpr int MAXG   = (CBS + (G - 1) * NADAPT) / G;  // 140 max groups
constexpr int NT     = 256;       // 4 waves/block; block = (gid, 4 slices)
constexpr int NBLK   = MAXG * SPLIT / (NT / 64);      // 1120 blocks
}

// Single kernel, ZERO workspace use. Each block deterministically recomputes
// its group's membership from wids (rank = index order — no ordering-dependent
// atomics), so every launch/replay does bit-identical work. Main loop: lane=r,
// no LDS, no barriers — pure streaming; TLP (4480 waves) hides L2/L3 latency.
__global__ __launch_bounds__(NT, 4)
void lora_main(const float* __restrict__ x,
               const int*   __restrict__ xids,
               const int*   __restrict__ wids,
               const float* __restrict__ A,
               float*       __restrict__ out)
{
    __shared__ int swids[CBS];
    __shared__ int hist[NADAPT];
    __shared__ int gmem[G];            // member combo ids of THIS block's group
    __shared__ int meta[2];            // [0]=wid (-1 if gid unused), [1]=base_rank

    const int t      = threadIdx.x;
    const int my_gid = blockIdx.x >> 3;              // group id (shared by 4 waves)

    // ---- deterministic group recompute (prologue, ~2us, amortized) ----
    for (int i = t; i < CBS; i += NT) swids[i] = wids[i];
    if (t < NADAPT) hist[t] = 0;
    if (t == 0) meta[0] = -1;
    __syncthreads();
    for (int i = t; i < CBS; i += NT) atomicAdd(&hist[swids[i]], 1);
    __syncthreads();
    if (t == 0) {                                    // scan: find my gid's wid
        int run = 0;
        for (int w = 0; w < NADAPT; ++w) {
            const int gb = run;
            run += (hist[w] + G - 1) >> 2;
            if (my_gid >= gb && my_gid < run) { meta[0] = w; meta[1] = (my_gid - gb) << 2; }
        }
    }
    __syncthreads();
    const int wid = meta[0];
    if (wid < 0) return;                             // unused gid: uniform exit
    const int base_rank = meta[1];
    const int cnt = min(G, hist[wid] - base_rank);   // 1..4, uniform in block
    // members: combos with this wid whose index-order rank falls in our window
    for (int i = t; i < CBS; i += NT) {
        if (swids[i] == wid) {
            int rk = 0;
            for (int j = 0; j < i; ++j) rk += (swids[j] == wid) ? 1 : 0;
            if (rk >= base_rank && rk < base_rank + G) gmem[rk - base_rank] = i;
        }
    }
    __syncthreads();

    // ---- main: wave (gid, s); lane = r. A coalesced, x per-lane streams ----
    const int wave = t >> 6;
    const int lane = t & 63;
    const int s    = ((blockIdx.x & 7) << 2) | wave; // k-slice 0..31

    const float* __restrict__ Ap =
        A + (size_t)wid * (K * R) + (size_t)(s * KS) * R + lane;

    int cidx[G];
    const float4* __restrict__ xp[G];
#pragma unroll
    for (int g = 0; g < G; ++g) {
        cidx[g] = (g < cnt) ? gmem[g] : gmem[0];
        const int tok = xids[cidx[g] * R + lane];
        xp[g] = (const float4*)(x + (size_t)tok * K + s * KS);
    }

    float acc[G] = {0.f, 0.f, 0.f, 0.f};

#pragma unroll
    for (int b = 0; b < NBODY; ++b) {
        // 32 coalesced A row-loads (256B/instr), shared across 4 combos
        float a[32];
#pragma unroll
        for (int j = 0; j < 32; ++j)
            a[j] = Ap[(size_t)(b * 32 + j) * R];

#pragma unroll
        for (int g = 0; g < G; ++g) {
            if (g < cnt) {
                float tacc = acc[g];
#pragma unroll
                for (int j = 0; j < 8; ++j) {        // 8 float4 = k b*32 .. +31
                    const float4 v = xp[g][b * 8 + j];
                    tacc = fmaf(v.x, a[j * 4 + 0], tacc);
                    tacc = fmaf(v.y, a[j * 4 + 1], tacc);
                    tacc = fmaf(v.z, a[j * 4 + 2], tacc);
                    tacc = fmaf(v.w, a[j * 4 + 3], tacc);
                }
                acc[g] = tacc;
            }
        }
    }

    // one fp32 atomic per (combo, r) per slice: 32 adds per output element
#pragma unroll
    for (int g = 0; g < G; ++g)
        if (g < cnt)
            atomicAdd(&out[cidx[g] * R + lane], acc[g]);
}

extern "C" void kernel_launch(void* const* d_in, const int* in_sizes, int n_in,
                              void* d_out, int out_size, void* d_ws, size_t ws_size,
                              hipStream_t stream)
{
    (void)in_sizes; (void)n_in; (void)d_ws; (void)ws_size;
    const float* x    = (const float*)d_in[0];
    const int*   xids = (const int*)d_in[1];
    const int*   wids = (const int*)d_in[2];
    const float* A    = (const float*)d_in[3];
    float* out        = (float*)d_out;

    // d_out is poisoned 0xAA before every launch; zero it, then accumulate.
    hipMemsetAsync(out, 0, (size_t)out_size * sizeof(float), stream);

    hipLaunchKernelGGL(lora_main, dim3(NBLK), dim3(NT), 0, stream,
                       x, xids, wids, A, out);
}

// Round 8
// 161.463 us; speedup vs baseline: 1.1410x; 1.1410x over previous
//
#include <hip/hip_runtime.h>
#include <stdint.h>

namespace {
constexpr int BATCH  = 512;
constexpr int CBS    = 320;       // combined batch size
constexpr int R      = 64;        // rank
constexpr int K      = 4096;
constexpr int NADAPT = 80;
constexpr int SPLIT  = 8;         // k-split; bid&7 -> XCD affinity for slice s
constexpr int KS     = K / SPLIT; // 512 k per block
constexpr int TK     = 64;        // k-tile (32 bf16 pairs) staged in LDS
constexpr int NTILES = KS / TK;   // 8
constexpr int NT     = 256;       // 4 waves
constexpr int NW     = NT / 64;
constexpr int G      = 4;         // combos per group (share one adapter's A)
constexpr int MAXG   = (CBS + (G - 1) * NADAPT) / G;  // 140 max groups
constexpr int NBLK   = MAXG * SPLIT;                  // 1120 blocks

constexpr size_t WS_XB_OFF = 0;   // ws holds ONLY the bf16 x image
constexpr size_t WS_NEEDED = (size_t)BATCH * K * 2;   // 4 MiB

__device__ inline uint16_t f2bf(float f) {   // RNE fp32 -> bf16
    uint32_t u = __float_as_uint(f);
    u += 0x7fffu + ((u >> 16) & 1u);
    return (uint16_t)(u >> 16);
}
__device__ inline float bflo(uint32_t u) { return __uint_as_float(u << 16); }
__device__ inline float bfhi(uint32_t u) { return __uint_as_float(u & 0xffff0000u); }
}

// ---- pre-pass: x fp32 -> bf16 in ws (halves x line-touches; ~12MB, ~3us) ----
__global__ __launch_bounds__(256)
void cvt_x(const float* __restrict__ x, uint16_t* __restrict__ xb)
{
    const int i = blockIdx.x * 256 + threadIdx.x;   // over BATCH*K/4 float4s
    const float4 v = ((const float4*)x)[i];
    ushort4 o;
    o.x = f2bf(v.x); o.y = f2bf(v.y); o.z = f2bf(v.z); o.w = f2bf(v.w);
    ((ushort4*)xb)[i] = o;
}

// ---- main: block (gid, s). Group membership recomputed deterministically
//      in-kernel (rank = index order, no ordering-dependent atomics) — the
//      R6 ws-metadata failure mode cannot occur. ----
__global__ __launch_bounds__(NT)
void lora_main(const int* __restrict__ xids,
               const int* __restrict__ wids,
               const float* __restrict__ A,
               const uint16_t* __restrict__ xb,
               float* __restrict__ out)
{
    __shared__ int swids[CBS];
    __shared__ int hist[NADAPT];
    __shared__ int gmem[G];
    __shared__ int meta[2];                      // [0]=wid or -1, [1]=base_rank
    // xs: packed bf16 pairs [g][p(32)][r'(64)] u32; r' = r ^ ((p>>3)<<4).
    __shared__ uint32_t xs[G * (TK / 2) * R];    // 32 KiB
    __shared__ float red[G * NW * R];            // 4 KiB

    const int t      = threadIdx.x;
    const int my_gid = blockIdx.x >> 3;
    const int s      = blockIdx.x & 7;           // slice -> XCD (bid%8 heuristic)

    // ---- deterministic group recompute ----
    for (int i = t; i < CBS; i += NT) swids[i] = wids[i];
    if (t < NADAPT) hist[t] = 0;
    if (t == 0) meta[0] = -1;
    __syncthreads();
    for (int i = t; i < CBS; i += NT) atomicAdd(&hist[swids[i]], 1);
    __syncthreads();
    if (t == 0) {
        int run = 0;
        for (int w = 0; w < NADAPT; ++w) {
            const int gb = run;
            run += (hist[w] + G - 1) >> 2;
            if (my_gid >= gb && my_gid < run) { meta[0] = w; meta[1] = (my_gid - gb) << 2; }
        }
    }
    __syncthreads();
    const int wid = meta[0];
    if (wid < 0) return;                         // uniform exit (pre-barriers ok)
    const int base_rank = meta[1];
    const int cnt = min(G, hist[wid] - base_rank);
    for (int i = t; i < CBS; i += NT) {
        if (swids[i] == wid) {
            int rk = 0;
            for (int j = 0; j < i; ++j) rk += (swids[j] == wid) ? 1 : 0;
            if (rk >= base_rank && rk < base_rank + G) gmem[rk - base_rank] = i;
        }
    }
    __syncthreads();

    // ---- roles ----
    const int wave = t >> 6;
    const int lane = t & 63;
    const int r4   = lane & 15;                  // lane owns r = 4*r4..+3
    const int kq   = lane >> 4;
    const int rw   = t >> 2;                     // staging row 0..63
    const int jq   = t & 3;                      // staging chunk: pairs [8jq,8jq+8)
    const int rsw  = rw ^ (jq << 4);             // write swizzle: 2-way banks

    const float* __restrict__ Aw = A + (size_t)wid * (K * R);

    int cidx[G];
    const uint4* __restrict__ xrow[G];
#pragma unroll
    for (int g = 0; g < G; ++g) {
        cidx[g] = (g < cnt) ? gmem[g] : gmem[0];
        const int tok = xids[cidx[g] * R + rw];
        // thread's 32B chunk of the row: pairs [jq*8, jq*8+8) = 2 uint4
        xrow[g] = (const uint4*)(xb + (size_t)tok * K + s * KS + jq * 16);
    }

    float4 acc[G];
#pragma unroll
    for (int g = 0; g < G; ++g) acc[g] = make_float4(0.f, 0.f, 0.f, 0.f);

    // prefetch tile 0 (all g): up to 8 independent 16B loads in flight
    uint4 p0[G], p1[G];
#pragma unroll
    for (int g = 0; g < G; ++g)
        if (g < cnt) { p0[g] = xrow[g][0]; p1[g] = xrow[g][1]; }

    const int rr = (4 * r4) ^ (wave << 4);       // read swizzle (p>>3 == wave)

    for (int tile = 0; tile < NTILES; ++tile) {
        // ---- write prefetched tile to LDS (straight u32 scatter, 2-way) ----
#pragma unroll
        for (int g = 0; g < G; ++g) {
            if (g < cnt) {
                uint32_t* dst = &xs[g * (TK / 2) * R + (jq * 8) * R + rsw];
                dst[0 * R] = p0[g].x; dst[1 * R] = p0[g].y;
                dst[2 * R] = p0[g].z; dst[3 * R] = p0[g].w;
                dst[4 * R] = p1[g].x; dst[5 * R] = p1[g].y;
                dst[6 * R] = p1[g].z; dst[7 * R] = p1[g].w;
            }
        }
        __syncthreads();

        // ---- prefetch next tile across compute ----
        if (tile + 1 < NTILES) {
            const int off = (tile + 1) * (TK / 2 / 4);   // uint4s per tile-row
#pragma unroll
            for (int g = 0; g < G; ++g)
                if (g < cnt) { p0[g] = xrow[g][off]; p1[g] = xrow[g][off + 1]; }
        }

        // ---- compute: wave covers pairs [wave*8, wave*8+8); i in {0,1} ----
#pragma unroll
        for (int i = 0; i < 2; ++i) {
            const int p  = wave * 8 + i * 4 + kq;        // pair index in tile
            const int k0 = s * KS + tile * TK + 2 * p;
            const float* __restrict__ Ap = Aw + (size_t)k0 * R + 4 * r4;
            const float4 a0 = *(const float4*)(Ap);      // k0   (reused x4 combos)
            const float4 a1 = *(const float4*)(Ap + R);  // k0+1
#pragma unroll
            for (int g = 0; g < G; ++g) {
                if (g < cnt) {
                    const uint4 f = *(const uint4*)&xs[g * (TK / 2) * R + p * R + rr];
                    acc[g].x = fmaf(bflo(f.x), a0.x, acc[g].x);
                    acc[g].y = fmaf(bflo(f.y), a0.y, acc[g].y);
                    acc[g].z = fmaf(bflo(f.z), a0.z, acc[g].z);
                    acc[g].w = fmaf(bflo(f.w), a0.w, acc[g].w);
                    acc[g].x = fmaf(bfhi(f.x), a1.x, acc[g].x);
                    acc[g].y = fmaf(bfhi(f.y), a1.y, acc[g].y);
                    acc[g].z = fmaf(bfhi(f.z), a1.z, acc[g].z);
                    acc[g].w = fmaf(bfhi(f.w), a1.w, acc[g].w);
                }
            }
        }
        __syncthreads();
    }

    // ---- reduce over kq lanes, then waves; one atomic per output element ----
#pragma unroll
    for (int g = 0; g < G; ++g) {
#pragma unroll
        for (int m = 16; m < 64; m <<= 1) {
            acc[g].x += __shfl_xor(acc[g].x, m, 64);
            acc[g].y += __shfl_xor(acc[g].y, m, 64);
            acc[g].z += __shfl_xor(acc[g].z, m, 64);
            acc[g].w += __shfl_xor(acc[g].w, m, 64);
        }
    }
    if (kq == 0) {
#pragma unroll
        for (int g = 0; g < G; ++g)
            *(float4*)&red[(g * NW + wave) * R + 4 * r4] = acc[g];
    }
    __syncthreads();
    {
        const int g = wave;                      // wave g writes combo g
        if (g < cnt) {
            const float sum = red[(g * NW + 0) * R + lane] + red[(g * NW + 1) * R + lane]
                            + red[(g * NW + 2) * R + lane] + red[(g * NW + 3) * R + lane];
            atomicAdd(&out[gmem[g] * R + lane], sum);
        }
    }
}

// ---- fallback (ws too small): R2-proven fp32 kernel, ungrouped ----
__global__ __launch_bounds__(NT)
void lora_fallback(const float* __restrict__ x,
                   const int*   __restrict__ xids,
                   const int*   __restrict__ wids,
                   const float* __restrict__ A,
                   float*       __restrict__ out)
{
    __shared__ float xsf[64 * R];
    __shared__ float red[NW * R];
    const int bid  = blockIdx.x;
    const int c    = bid >> 3;
    const int sl   = bid & 7;
    const int t    = threadIdx.x;
    const int wave = t >> 6;
    const int lane = t & 63;
    const int r4   = lane & 15;
    const int kq   = lane >> 4;
    const int wid  = wids[c];
    const float* __restrict__ Aw = A + (size_t)wid * (K * R);
    const int rw  = t >> 2;
    const int jq  = t & 3;
    const int tok = xids[c * R + rw];
    const float* __restrict__ xrow = x + (size_t)tok * K + sl * KS + jq * 16;
    float4 acc = make_float4(0.f, 0.f, 0.f, 0.f);
    for (int tile = 0; tile < KS / 64; ++tile) {
        const float4* src = (const float4*)(xrow + tile * 64);
#pragma unroll
        for (int ii = 0; ii < 4; ++ii) {
            float4 v = src[ii];
            const int kk = jq * 16 + ii * 4;
            xsf[(kk + 0) * R + rw] = v.x;
            xsf[(kk + 1) * R + rw] = v.y;
            xsf[(kk + 2) * R + rw] = v.z;
            xsf[(kk + 3) * R + rw] = v.w;
        }
        __syncthreads();
        const int kw = wave * 16 + kq;
        const float* __restrict__ Ap =
            Aw + (size_t)(sl * KS + tile * 64 + kw) * R + 4 * r4;
#pragma unroll
        for (int i = 0; i < 4; ++i) {
            float4 av = *(const float4*)(Ap + (size_t)(4 * i) * R);
            float4 xv = *(const float4*)(&xsf[(kw + 4 * i) * R + 4 * r4]);
            acc.x = fmaf(xv.x, av.x, acc.x);
            acc.y = fmaf(xv.y, av.y, acc.y);
            acc.z = fmaf(xv.z, av.z, acc.z);
            acc.w = fmaf(xv.w, av.w, acc.w);
        }
        __syncthreads();
    }
#pragma unroll
    for (int m = 16; m < 64; m <<= 1) {
        acc.x += __shfl_xor(acc.x, m, 64);
        acc.y += __shfl_xor(acc.y, m, 64);
        acc.z += __shfl_xor(acc.z, m, 64);
        acc.w += __shfl_xor(acc.w, m, 64);
    }
    if (kq == 0) {
        float* rd = &red[wave * R + 4 * r4];
        rd[0] = acc.x; rd[1] = acc.y; rd[2] = acc.z; rd[3] = acc.w;
    }
    __syncthreads();
    if (wave == 0) {
        float sum = red[lane] + red[R + lane] + red[2 * R + lane] + red[3 * R + lane];
        atomicAdd(&out[c * R + lane], sum);
    }
}

extern "C" void kernel_launch(void* const* d_in, const int* in_sizes, int n_in,
                              void* d_out, int out_size, void* d_ws, size_t ws_size,
                              hipStream_t stream)
{
    (void)in_sizes; (void)n_in;
    const float* x    = (const float*)d_in[0];
    const int*   xids = (const int*)d_in[1];
    const int*   wids = (const int*)d_in[2];
    const float* A    = (const float*)d_in[3];
    float* out        = (float*)d_out;

    // d_out is poisoned 0xAA before every launch; zero it, then accumulate.
    hipMemsetAsync(out, 0, (size_t)out_size * sizeof(float), stream);

    if (ws_size >= WS_NEEDED) {
        uint16_t* xb = (uint16_t*)((char*)d_ws + WS_XB_OFF);
        hipLaunchKernelGGL(cvt_x, dim3(BATCH * K / 4 / 256), dim3(256), 0, stream, x, xb);
        hipLaunchKernelGGL(lora_main, dim3(NBLK), dim3(NT), 0, stream,
                           xids, wids, A, xb, out);
    } else {
        hipLaunchKernelGGL(lora_fallback, dim3(CBS * SPLIT), dim3(NT), 0, stream,
                           x, xids, wids, A, out);
    }
}